// Round 4
// baseline (770.870 us; speedup 1.0000x reference)
//
#include <hip/hip_runtime.h>
#include <cstdint>
#include <cstddef>

#define DIM 128
#define NG 128
#define NCLS 10
#define SCAN_B 1024
#define PSLICE 8

// ---------------- preprocessing ----------------

__global__ void k_hist(const int* __restrict__ row, int E, int* __restrict__ cnt,
                       int* __restrict__ slot) {
  int stride = gridDim.x * blockDim.x;
  for (int i = blockIdx.x * blockDim.x + threadIdx.x; i < E; i += stride)
    slot[i] = atomicAdd(&cnt[row[i]], 1);
}

__global__ void k_dis(const int* __restrict__ cnt, float* __restrict__ dis, int N) {
  int i = blockIdx.x * blockDim.x + threadIdx.x;
  if (i < N) {
    float d = (float)(cnt[i] + 1);  // +1 self loop
    dis[i] = 1.0f / sqrtf(d);
  }
}

__global__ void k_scan1(const int* __restrict__ in, int* __restrict__ inc,
                        int* __restrict__ bsum, int N) {
  __shared__ int s[SCAN_B];
  int t = threadIdx.x;
  int gi = blockIdx.x * SCAN_B + t;
  s[t] = (gi < N) ? in[gi] : 0;
  __syncthreads();
  for (int off = 1; off < SCAN_B; off <<= 1) {
    int x = (t >= off) ? s[t - off] : 0;
    __syncthreads();
    s[t] += x;
    __syncthreads();
  }
  if (gi < N) inc[gi] = s[t];
  if (t == SCAN_B - 1) bsum[blockIdx.x] = s[t];
}

__global__ void k_scan2(const int* __restrict__ bsum, int* __restrict__ boff, int nb) {
  if (blockIdx.x == 0 && threadIdx.x == 0) {
    int acc = 0;
    for (int i = 0; i < nb; ++i) { boff[i] = acc; acc += bsum[i]; }
  }
}

__global__ void k_scan3(const int* __restrict__ inc, const int* __restrict__ cnt,
                        const int* __restrict__ boff, int* __restrict__ offs,
                        int N, int E) {
  int i = blockIdx.x * blockDim.x + threadIdx.x;
  if (i < N) offs[i] = inc[i] - cnt[i] + boff[i / SCAN_B];
  if (i == 0) offs[N] = E;
}

__global__ void k_scatter(const int* __restrict__ rw, const int* __restrict__ cl, int E,
                          const float* __restrict__ dis, const int* __restrict__ offs,
                          const int* __restrict__ slot, int2* __restrict__ csr) {
  int stride = gridDim.x * blockDim.x;
  for (int i = blockIdx.x * blockDim.x + threadIdx.x; i < E; i += stride) {
    int r = rw[i], c = cl[i];
    int pos = offs[r] + slot[i];
    csr[pos] = make_int2(c, __float_as_int(dis[c]));
  }
}

// ---------------- GEMM: H = X @ W + b  (fp32, W in LDS, 8x8 per lane) ----------------
// wave = 4 row-groups x 16 col-lanes; per lane 8 rows x 8 cols -> wave covers
// 32 rows x 128 cols; block (4 waves) = 128 rows. Per k: 2 ds_read_b128 +
// 8 shfl + 64 FMA -> VALU-bound.

__global__ __launch_bounds__(256, 2) void k_gemm(
    const float* __restrict__ X, const float* __restrict__ W,
    const float* __restrict__ bias, float* __restrict__ H, int N) {
  __shared__ float Ws[DIM * DIM];  // 64 KiB
  int t = threadIdx.x;
  for (int i = t * 4; i < DIM * DIM; i += 1024)
    *(float4*)(Ws + i) = *(const float4*)(W + i);

  int lane = t & 63;
  int wv = t >> 6;          // wave in block (0..3)
  int g = lane >> 4;        // row group in wave (0..3)
  int tx = lane & 15;       // col lane (0..15)
  int colb = tx * 8;
  int lane48 = lane & 48;
  float4 bv0 = *(const float4*)(bias + colb);
  float4 bv1 = *(const float4*)(bias + colb + 4);
  __syncthreads();

  const int ntiles = (N + 127) / 128;
  for (int tile = blockIdx.x; tile < ntiles; tile += gridDim.x) {
    int row0 = tile * 128 + wv * 32 + g * 8;  // this lane's 8 rows
    float xr[8][8];
#pragma unroll
    for (int j = 0; j < 8; ++j) {
      int r = row0 + j;
      if (r < N) {
        *(float4*)&xr[j][0] = *(const float4*)(X + (size_t)r * DIM + colb);
        *(float4*)&xr[j][4] = *(const float4*)(X + (size_t)r * DIM + colb + 4);
      } else {
#pragma unroll
        for (int c = 0; c < 8; ++c) xr[j][c] = 0.f;
      }
    }
    float acc[8][8];
#pragma unroll
    for (int j = 0; j < 8; ++j)
#pragma unroll
      for (int c = 0; c < 8; ++c) acc[j][c] = 0.f;

    for (int k8 = 0; k8 < DIM; k8 += 8) {
      int src = lane48 | (k8 >> 3);  // source lane for this k-octet
#pragma unroll
      for (int c8 = 0; c8 < 8; ++c8) {
        int k = k8 + c8;
        float4 w0 = *(const float4*)(Ws + k * DIM + colb);
        float4 w1 = *(const float4*)(Ws + k * DIM + colb + 4);
#pragma unroll
        for (int j = 0; j < 8; ++j) {
          float x = __shfl(xr[j][c8], src);
          acc[j][0] = fmaf(x, w0.x, acc[j][0]);
          acc[j][1] = fmaf(x, w0.y, acc[j][1]);
          acc[j][2] = fmaf(x, w0.z, acc[j][2]);
          acc[j][3] = fmaf(x, w0.w, acc[j][3]);
          acc[j][4] = fmaf(x, w1.x, acc[j][4]);
          acc[j][5] = fmaf(x, w1.y, acc[j][5]);
          acc[j][6] = fmaf(x, w1.z, acc[j][6]);
          acc[j][7] = fmaf(x, w1.w, acc[j][7]);
        }
      }
    }
#pragma unroll
    for (int j = 0; j < 8; ++j) {
      int r = row0 + j;
      if (r < N) {
        float4 o0, o1;
        o0.x = acc[j][0] + bv0.x; o0.y = acc[j][1] + bv0.y;
        o0.z = acc[j][2] + bv0.z; o0.w = acc[j][3] + bv0.w;
        o1.x = acc[j][4] + bv1.x; o1.y = acc[j][5] + bv1.y;
        o1.z = acc[j][6] + bv1.z; o1.w = acc[j][7] + bv1.w;
        *(float4*)(H + (size_t)r * DIM + colb) = o0;
        *(float4*)(H + (size_t)r * DIM + colb + 4) = o1;
      }
    }
  }
}

// ---------------- aggregation ----------------
// out[r] = relu(dis[r]*(sum_c dis[c]*H[c] + dis[r]*H[r]))
// wave per row; two 32-lane halves, each unrolled 4x -> 8 row-gathers in flight.

__global__ __launch_bounds__(256) void k_agg(
    const float* __restrict__ H, float* __restrict__ out,
    const int2* __restrict__ csr, const int* __restrict__ offs,
    const float* __restrict__ dis, int N) {
  int wid = (int)(((size_t)blockIdx.x * blockDim.x + threadIdx.x) >> 6);
  int lane = threadIdx.x & 63;
  if (wid >= N) return;
  int half = lane >> 5;
  int q = lane & 31;
  int s = offs[wid], e = offs[wid + 1];
  int cnt = e - s;
  float dr = dis[wid];
  float4 self = *(const float4*)(H + (size_t)wid * DIM + q * 4);
  float4 a0 = {0.f, 0.f, 0.f, 0.f};
  float4 a1 = {0.f, 0.f, 0.f, 0.f};
  float4 a2 = {0.f, 0.f, 0.f, 0.f};
  float4 a3 = {0.f, 0.f, 0.f, 0.f};
  int i = half;
  for (; i + 6 < cnt; i += 8) {
    int2 e0 = csr[s + i];
    int2 e1 = csr[s + i + 2];
    int2 e2 = csr[s + i + 4];
    int2 e3 = csr[s + i + 6];
    float4 h0 = *(const float4*)(H + (size_t)e0.x * DIM + q * 4);
    float4 h1 = *(const float4*)(H + (size_t)e1.x * DIM + q * 4);
    float4 h2 = *(const float4*)(H + (size_t)e2.x * DIM + q * 4);
    float4 h3 = *(const float4*)(H + (size_t)e3.x * DIM + q * 4);
    float w0 = __int_as_float(e0.y);
    float w1 = __int_as_float(e1.y);
    float w2 = __int_as_float(e2.y);
    float w3 = __int_as_float(e3.y);
    a0.x = fmaf(w0, h0.x, a0.x); a0.y = fmaf(w0, h0.y, a0.y);
    a0.z = fmaf(w0, h0.z, a0.z); a0.w = fmaf(w0, h0.w, a0.w);
    a1.x = fmaf(w1, h1.x, a1.x); a1.y = fmaf(w1, h1.y, a1.y);
    a1.z = fmaf(w1, h1.z, a1.z); a1.w = fmaf(w1, h1.w, a1.w);
    a2.x = fmaf(w2, h2.x, a2.x); a2.y = fmaf(w2, h2.y, a2.y);
    a2.z = fmaf(w2, h2.z, a2.z); a2.w = fmaf(w2, h2.w, a2.w);
    a3.x = fmaf(w3, h3.x, a3.x); a3.y = fmaf(w3, h3.y, a3.y);
    a3.z = fmaf(w3, h3.z, a3.z); a3.w = fmaf(w3, h3.w, a3.w);
  }
  for (; i < cnt; i += 2) {
    int2 e0 = csr[s + i];
    float4 h0 = *(const float4*)(H + (size_t)e0.x * DIM + q * 4);
    float w0 = __int_as_float(e0.y);
    a0.x = fmaf(w0, h0.x, a0.x); a0.y = fmaf(w0, h0.y, a0.y);
    a0.z = fmaf(w0, h0.z, a0.z); a0.w = fmaf(w0, h0.w, a0.w);
  }
  float ax = (a0.x + a1.x) + (a2.x + a3.x);
  float ay = (a0.y + a1.y) + (a2.y + a3.y);
  float az = (a0.z + a1.z) + (a2.z + a3.z);
  float aw = (a0.w + a1.w) + (a2.w + a3.w);
  ax += __shfl_xor(ax, 32);
  ay += __shfl_xor(ay, 32);
  az += __shfl_xor(az, 32);
  aw += __shfl_xor(aw, 32);
  if (lane < 32) {
    float4 o;
    o.x = fmaxf(dr * fmaf(dr, self.x, ax), 0.f);
    o.y = fmaxf(dr * fmaf(dr, self.y, ay), 0.f);
    o.z = fmaxf(dr * fmaf(dr, self.z, az), 0.f);
    o.w = fmaxf(dr * fmaf(dr, self.w, aw), 0.f);
    *(float4*)(out + (size_t)wid * DIM + q * 4) = o;
  }
}

// ---------------- pooling ----------------

__global__ void k_bounds(const int* __restrict__ batch, int N, int G,
                         int* __restrict__ starts) {
  int i = blockIdx.x * blockDim.x + threadIdx.x;
  if (i >= N) return;
  int b = batch[i];
  int pb = (i == 0) ? -1 : batch[i - 1];
  for (int g = pb + 1; g <= b; ++g) starts[g] = i;
  if (i == N - 1) {
    for (int g = b + 1; g <= G; ++g) starts[g] = N;
  }
}

__global__ void k_pool1(const float* __restrict__ A, const int* __restrict__ starts,
                        float* __restrict__ part) {
  int g = blockIdx.x / PSLICE, sl = blockIdx.x % PSLICE;
  int c = threadIdx.x;  // 128
  int s = starts[g], e = starts[g + 1];
  int len = e - s;
  int ns = s + (len * sl) / PSLICE;
  int ne = s + (len * (sl + 1)) / PSLICE;
  float sum = 0.f, mx = -INFINITY;
  for (int n = ns; n < ne; ++n) {
    float v = A[(size_t)n * DIM + c];
    sum += v;
    mx = fmaxf(mx, v);
  }
  part[((size_t)(g * PSLICE + sl) * 2 + 0) * DIM + c] = sum;
  part[((size_t)(g * PSLICE + sl) * 2 + 1) * DIM + c] = mx;
}

__global__ void k_pool2(const float* __restrict__ part, const int* __restrict__ starts,
                        float* __restrict__ GF) {
  int g = blockIdx.x;
  int c = threadIdx.x;  // 128
  float sum = 0.f, mx = -INFINITY;
  for (int sl = 0; sl < PSLICE; ++sl) {
    sum += part[((size_t)(g * PSLICE + sl) * 2 + 0) * DIM + c];
    mx = fmaxf(mx, part[((size_t)(g * PSLICE + sl) * 2 + 1) * DIM + c]);
  }
  int cntg = starts[g + 1] - starts[g];
  GF[(size_t)g * 256 + c] = sum / ((float)cntg + 1e-12f);
  GF[(size_t)g * 256 + 128 + c] = mx;
}

// ---------------- MLP ----------------

__global__ void k_mlp1(const float* __restrict__ GF, const float* __restrict__ Wm1,
                       const float* __restrict__ bm1, float* __restrict__ H1) {
  __shared__ float gs[256];
  int g = blockIdx.x, j = threadIdx.x;  // 128 threads
  gs[j] = GF[(size_t)g * 256 + j];
  gs[j + 128] = GF[(size_t)g * 256 + 128 + j];
  __syncthreads();
  float acc = bm1[j];
#pragma unroll 8
  for (int k = 0; k < 256; ++k) acc = fmaf(gs[k], Wm1[k * DIM + j], acc);
  H1[(size_t)g * DIM + j] = fmaxf(acc, 0.f);
}

__global__ void k_mlp2(const float* __restrict__ H1, const float* __restrict__ Wm2,
                       const float* __restrict__ bm2, float* __restrict__ out) {
  __shared__ float hs[DIM];
  int g = blockIdx.x, j = threadIdx.x;  // 64 threads
  hs[j] = H1[(size_t)g * DIM + j];
  hs[j + 64] = H1[(size_t)g * DIM + j + 64];
  __syncthreads();
  if (j < NCLS) {
    float acc = bm2[j];
#pragma unroll 8
    for (int k = 0; k < DIM; ++k) acc = fmaf(hs[k], Wm2[k * NCLS + j], acc);
    out[(size_t)g * NCLS + j] = acc;
  }
}

// ---------------- host ----------------

static inline size_t al256(size_t x) { return (x + 255) & ~(size_t)255; }

extern "C" void kernel_launch(void* const* d_in, const int* in_sizes, int n_in,
                              void* d_out, int out_size, void* d_ws, size_t ws_size,
                              hipStream_t stream) {
  const float* X = (const float*)d_in[0];
  const int* EI = (const int*)d_in[1];
  const int* batch = (const int*)d_in[2];
  const float* W1 = (const float*)d_in[4];
  const float* b1 = (const float*)d_in[5];
  const float* W2 = (const float*)d_in[6];
  const float* b2 = (const float*)d_in[7];
  const float* W3 = (const float*)d_in[8];
  const float* b3 = (const float*)d_in[9];
  const float* Wm1 = (const float*)d_in[10];
  const float* bm1 = (const float*)d_in[11];
  const float* Wm2 = (const float*)d_in[12];
  const float* bm2 = (const float*)d_in[13];
  float* OUT = (float*)d_out;

  const int N = in_sizes[0] / DIM;
  const int E = in_sizes[1] / 2;
  const int G = NG;
  const int nb = (N + SCAN_B - 1) / SCAN_B;

  const int* EI_row = EI;
  const int* EI_col = EI + E;

  char* p = (char*)d_ws;
  size_t off = 0;
  auto take = [&](size_t bytes) { void* r = p + off; off = al256(off + bytes); return r; };

  int* cnt = (int*)take((size_t)N * 4);
  int* slot = (int*)take((size_t)E * 4);
  int* inc = (int*)take((size_t)N * 4);
  int* offs = (int*)take((size_t)(N + 1) * 4);
  int* bsum = (int*)take((size_t)nb * 4);
  int* boff = (int*)take((size_t)nb * 4);
  int* starts = (int*)take((size_t)(G + 1) * 4);
  float* dis = (float*)take((size_t)N * 4);
  int2* csr = (int2*)take((size_t)E * 8);
  float* B = (float*)take((size_t)N * DIM * 4);
  float* A = (float*)take((size_t)N * DIM * 4);
  float* part = (float*)take((size_t)G * PSLICE * 2 * DIM * 4);
  float* GF = (float*)take((size_t)G * 256 * 4);
  float* H1 = (float*)take((size_t)G * DIM * 4);
  (void)ws_size; (void)n_in; (void)out_size;

  hipMemsetAsync(cnt, 0, (size_t)N * 4, stream);

  // degree + dis (hist also records per-edge slot within its row)
  k_hist<<<1024, 256, 0, stream>>>(EI_row, E, cnt, slot);
  k_dis<<<(N + 255) / 256, 256, 0, stream>>>(cnt, dis, N);
  // exclusive scan -> CSR offsets
  k_scan1<<<nb, SCAN_B, 0, stream>>>(cnt, inc, bsum, N);
  k_scan2<<<1, 1, 0, stream>>>(bsum, boff, nb);
  k_scan3<<<(N + 255) / 256, 256, 0, stream>>>(inc, cnt, boff, offs, N, E);
  // scatter edges into packed CSR {col, w}
  k_scatter<<<1024, 256, 0, stream>>>(EI_row, EI_col, E, dis, offs, slot, csr);

  const int aggBlocks = (int)(((size_t)N * 64 + 255) / 256);

  // layer 1
  k_gemm<<<512, 256, 0, stream>>>(X, W1, b1, B, N);
  k_agg<<<aggBlocks, 256, 0, stream>>>(B, A, csr, offs, dis, N);
  // layer 2
  k_gemm<<<512, 256, 0, stream>>>(A, W2, b2, B, N);
  k_agg<<<aggBlocks, 256, 0, stream>>>(B, A, csr, offs, dis, N);
  // layer 3
  k_gemm<<<512, 256, 0, stream>>>(A, W3, b3, B, N);
  k_agg<<<aggBlocks, 256, 0, stream>>>(B, A, csr, offs, dis, N);

  // pooling
  k_bounds<<<(N + 255) / 256, 256, 0, stream>>>(batch, N, G, starts);
  k_pool1<<<G * PSLICE, DIM, 0, stream>>>(A, starts, part);
  k_pool2<<<G, DIM, 0, stream>>>(part, starts, GF);

  // MLP head
  k_mlp1<<<G, DIM, 0, stream>>>(GF, Wm1, bm1, H1);
  k_mlp2<<<G, 64, 0, stream>>>(H1, Wm2, bm2, OUT);
}